// Round 5
// baseline (354.987 us; speedup 1.0000x reference)
//
#include <hip/hip_runtime.h>

#define BB 2
#define SS 2048
#define EE 2048
#define HH 16
#define DD 128
#define SE (3 * EE)  // QKV row stride

typedef __bf16 bf16x8 __attribute__((ext_vector_type(8)));
typedef unsigned short u16x8 __attribute__((ext_vector_type(8)));
typedef float f32x4 __attribute__((ext_vector_type(4)));
typedef unsigned long long u64;
typedef u64 u64x2 __attribute__((ext_vector_type(2)));

__device__ __forceinline__ unsigned short f32_to_bf16(float f) {
  unsigned int u = __builtin_bit_cast(unsigned int, f);
  u += 0x7FFFu + ((u >> 16) & 1u);  // RNE
  return (unsigned short)(u >> 16);
}

__device__ __forceinline__ unsigned int cvt_pk_bf16(float lo, float hi) {
  unsigned int r;
  asm("v_cvt_pk_bf16_f32 %0, %1, %2" : "=v"(r) : "v"(lo), "v"(hi));
  return r;
}

__device__ __forceinline__ void gll16(const void* g, const void* lds) {
  __builtin_amdgcn_global_load_lds(
      (const __attribute__((address_space(1))) unsigned int*)g,
      (__attribute__((address_space(3))) unsigned int*)lds, 16, 0, 0);
}

__device__ __forceinline__ bf16x8 lds_frag(const unsigned short* p) {
  return __builtin_bit_cast(bf16x8, *(const u16x8*)p);
}

// ---------------- cast x: fp32 -> bf16 ----------------
__global__ void k_cast_bf16(const float* __restrict__ x, unsigned short* __restrict__ y) {
  int i = blockIdx.x * 256 + threadIdx.x;
  float4 v = ((const float4*)x)[i];
  ushort4 o;
  o.x = f32_to_bf16(v.x); o.y = f32_to_bf16(v.y);
  o.z = f32_to_bf16(v.z); o.w = f32_to_bf16(v.w);
  ((ushort4*)y)[i] = o;
}

// ---- all four W [E,E] fp32 -> Wt [E,E] bf16 (transposed), z selects ----
__global__ void k_transpose_w4(const float* __restrict__ W0, const float* __restrict__ W1,
                               const float* __restrict__ W2, const float* __restrict__ W3,
                               unsigned short* __restrict__ WtBase) {
  const float* W = blockIdx.z == 0 ? W0 : blockIdx.z == 1 ? W1 : blockIdx.z == 2 ? W2 : W3;
  unsigned short* Wt = WtBase + (size_t)blockIdx.z * EE * EE;
  __shared__ float tile[32][33];
  int n0 = blockIdx.x * 32, k0 = blockIdx.y * 32;
  int t = threadIdx.x, r = t >> 5, c = t & 31;
  for (int i = 0; i < 32; i += 8)
    tile[r + i][c] = W[(size_t)(k0 + r + i) * EE + n0 + c];
  __syncthreads();
  for (int i = 0; i < 32; i += 8)
    Wt[(size_t)(n0 + r + i) * EE + k0 + c] = f32_to_bf16(tile[c][r + i]);
}

// ---------------- GEMM: C[M,N] = A[M,K] @ Bt[N,K]^T ----
// R4-verified: 128x128, BK=64, XOR chunk swizzle (0 conflicts), single-buffer
// 2-barrier, 4 blocks/CU TLP. QKV call writes the V third directly to the
// per-head transposed Vt (fused transpose, saves k_transpose_v).
template <int OUTF32>
__global__ __launch_bounds__(256, 4) void k_gemm_bt(
    const unsigned short* __restrict__ A, const unsigned short* __restrict__ Bt,
    void* __restrict__ Cout, const float* __restrict__ bias,
    unsigned short* __restrict__ VtOut, int K, int N) {
  __shared__ unsigned short As[128 * 64];
  __shared__ unsigned short Bs[128 * 64];
  const int tid = threadIdx.x;
  const int l = tid & 63, w = tid >> 6;
  const int m0 = blockIdx.y * 128, n0 = blockIdx.x * 128;
  const int tm = l & 15, qc = l >> 4;
  const int swz = tm & 7;
  const int m_base = (w >> 1) * 64, n_base = (w & 1) * 64;
  f32x4 acc[4][4] = {};

  for (int k0 = 0; k0 < K; k0 += 64) {
    for (int is = 0; is < 4; ++is) {
      int o = (w * 4 + is) * 1024 + l * 16;        // byte offset = LDS slot
      int row = o >> 7, slot = (o >> 4) & 7;
      int c = slot ^ (row & 7);                    // global chunk for this slot
      gll16(&A[(size_t)(m0 + row) * K + k0 + c * 8], ((const char*)As) + o);
      gll16(&Bt[(size_t)(n0 + row) * K + k0 + c * 8], ((const char*)Bs) + o);
    }
    __syncthreads();
    for (int ks = 0; ks < 2; ++ks) {
      bf16x8 a[4], b[4];
      for (int im = 0; im < 4; ++im)
        a[im] = lds_frag(&As[(m_base + im * 16 + tm) * 64 + (((ks * 4 + qc) ^ swz) << 3)]);
      for (int in = 0; in < 4; ++in)
        b[in] = lds_frag(&Bs[(n_base + in * 16 + tm) * 64 + (((ks * 4 + qc) ^ swz) << 3)]);
      for (int im = 0; im < 4; ++im)
        for (int in = 0; in < 4; ++in)
          acc[im][in] = __builtin_amdgcn_mfma_f32_16x16x32_bf16(a[im], b[in], acc[im][in], 0, 0, 0);
    }
    __syncthreads();
  }

  if (!OUTF32 && n0 >= 2 * EE) {
    // V third: write per-head transposed directly. col -> (h,d); row -> (b,s).
    for (int im = 0; im < 4; ++im)
      for (int in = 0; in < 4; ++in) {
        int row0 = m0 + m_base + im * 16 + qc * 4;    // s base (4 consecutive)
        int col = n0 + n_base + in * 16 + tm - 2 * EE; // v index in [0,2048)
        int b = row0 >> 11, s = row0 & 2047;
        int h = col >> 7, d = col & 127;
        ushort4 o;
        o.x = f32_to_bf16(acc[im][in][0]);
        o.y = f32_to_bf16(acc[im][in][1]);
        o.z = f32_to_bf16(acc[im][in][2]);
        o.w = f32_to_bf16(acc[im][in][3]);
        *(ushort4*)&VtOut[((size_t)((b * HH + h) * DD + d) << 11) + s] = o;
      }
    return;
  }

  for (int im = 0; im < 4; ++im)
    for (int in = 0; in < 4; ++in)
      for (int r = 0; r < 4; ++r) {
        int row = m0 + m_base + im * 16 + (l >> 4) * 4 + r;
        int col = n0 + n_base + in * 16 + tm;
        if (OUTF32)
          ((float*)Cout)[(size_t)row * N + col] = acc[im][in][r] + bias[col];
        else
          ((unsigned short*)Cout)[(size_t)row * N + col] = f32_to_bf16(acc[im][in][r]);
      }
}

// ---------------- flash-style causal attention with ALiBi ----
// SWAPPED-OPERAND version: S = mfma(K,Q) puts col=q=tm (lane-fixed), row=j.
// PV uses a per-lane j-permutation pi(qc*8+e) = (e>>2)*16 + qc*4 + (e&3),
// valid because sum over j is permutation-invariant when applied to BOTH
// P and V. Under pi, each lane's P-fragment is exactly its own QK^T output
// (2x v_cvt_pk_bf16_f32 per kn, ZERO cross-lane traffic, ZERO LDS), and
// V-fragments are two 8B reads per (dc,k2) from the staged swizzled V tile.
// Deletes per iter: 32 ds_write_b16 + lgkmcnt(0) join + 4 ds_read_b128 +
// all Ps bank conflicts. Ps LDS freed: 80KB -> 64KB. Epilogue: ushort4.
__global__ __launch_bounds__(256, 2) void k_attn(
    const unsigned short* __restrict__ QKV, const unsigned short* __restrict__ Vt,
    unsigned short* __restrict__ ctx) {
  __shared__ unsigned short smem[32768];  // 64 KB: K/V double buffer (Q staged transiently in buf1)
  const int tid = threadIdx.x;
  const int l = tid & 63, w = tid >> 6;
  const int tm = l & 15, qc = l >> 4;
  const int bh = blockIdx.x, b = bh >> 4, h = bh & 15;
  const int rank = blockIdx.y;
  const int t = (rank < 8) ? (15 - rank) : (rank - 8);
  const int q0 = t * 128;
  const int n_it = 2 * t + 2;
  const float c1 = 0.12751676f;  // log2(e)/sqrt(128)
  const float slopeL = exp2f(-0.5f * (float)(h + 1)) * c1;

  const unsigned short* Qg = QKV + h * DD;
  const unsigned short* Kg = QKV + EE + h * DD;
  const unsigned short* Vg = Vt + (size_t)bh * DD * SS;

  for (int is = 0; is < 8; ++is) {
    int idx = (w * 8 + is) * 64 + l;
    int row = idx >> 4, c = (idx & 15) ^ (row & 7);
    gll16(&Qg[(size_t)(b * SS + q0 + row) * SE + c * 8], ((char*)smem) + 32768 + idx * 16);
  }
  for (int is = 0; is < 4; ++is) {
    int idx = (w * 4 + is) * 64 + l;
    int kr = idx >> 4, kc = (idx & 15) ^ (kr & 7);
    gll16(&Kg[(size_t)(b * SS + kr) * SE + kc * 8], ((char*)smem) + idx * 16);
    int vr = idx >> 3, vc = (idx & 7) ^ (vr & 7);
    gll16(&Vg[(size_t)vr * SS + vc * 8], ((char*)smem) + 16384 + idx * 16);
  }
  __syncthreads();
  bf16x8 qf[2][4];
  for (int im = 0; im < 2; ++im)
    for (int kk = 0; kk < 4; ++kk) {
      int row = w * 32 + im * 16 + tm;
      qf[im][kk] = lds_frag(&smem[16384 + (row * 16 + ((kk * 4 + qc) ^ (tm & 7))) * 8]);
    }
  __syncthreads();

  float lr[2] = {};
  f32x4 o[2][8] = {};
  const int qA = q0 + w * 32 + tm;       // q for im=0 (lane-fixed)

  for (int it = 0; it < n_it; ++it) {
    const int kt = it * 64;
    const unsigned short* K_ = smem + (it & 1) * 16384;
    const unsigned short* V_ = K_ + 8192;
    if (it + 1 < n_it) {
      char* Kd = ((char*)smem) + ((it + 1) & 1) * 32768;
      int ktn = kt + 64;
      for (int is = 0; is < 4; ++is) {
        int idx = (w * 4 + is) * 64 + l;
        int kr = idx >> 4, kc = (idx & 15) ^ (kr & 7);
        gll16(&Kg[(size_t)(b * SS + ktn + kr) * SE + kc * 8], Kd + idx * 16);
        int vr = idx >> 3, vc = (idx & 7) ^ (vr & 7);
        gll16(&Vg[(size_t)vr * SS + ktn + vc * 8], Kd + 16384 + idx * 16);
      }
    }
    const bool full = (kt + 64 <= q0);

    unsigned int pfu[2][2][4];  // [im][k2][u32 slot] -> bf16x8 P-fragments
#pragma unroll
    for (int kn = 0; kn < 4; ++kn) {
      bf16x8 kf[4];
#pragma unroll
      for (int kk = 0; kk < 4; ++kk) {
        int row = kn * 16 + tm;
        kf[kk] = lds_frag(&K_[(row * 16 + ((kk * 4 + qc) ^ (tm & 7))) * 8]);
      }
      f32x4 a0 = {}, a1 = {};
#pragma unroll
      for (int kk = 0; kk < 4; ++kk) {
        a0 = __builtin_amdgcn_mfma_f32_16x16x32_bf16(kf[kk], qf[0][kk], a0, 0, 0, 0);
        a1 = __builtin_amdgcn_mfma_f32_16x16x32_bf16(kf[kk], qf[1][kk], a1, 0, 0, 0);
      }
      const int jb = kt + kn * 16 + qc * 4;   // j for r=0
#pragma unroll
      for (int im = 0; im < 2; ++im) {
        const f32x4 av = im ? a1 : a0;
        const int dbase = jb - (qA + im * 16);  // d for r=0
        const float fb = slopeL * (float)dbase;
        float p[4];
#pragma unroll
        for (int r = 0; r < 4; ++r) {
          float arg = av[r] * c1 + (fb + slopeL * (float)r);
          if (!full && dbase + r > 0) arg = -1e30f;
          p[r] = __builtin_amdgcn_exp2f(arg);
        }
        lr[im] += (p[0] + p[1]) + (p[2] + p[3]);
        pfu[im][kn >> 1][(kn & 1) * 2]     = cvt_pk_bf16(p[0], p[1]);
        pfu[im][kn >> 1][(kn & 1) * 2 + 1] = cvt_pk_bf16(p[2], p[3]);
      }
    }
    bf16x8 pf[2][2];
#pragma unroll
    for (int im = 0; im < 2; ++im)
#pragma unroll
      for (int k2 = 0; k2 < 2; ++k2)
        pf[im][k2] = __builtin_bit_cast(bf16x8, *(unsigned int(*)[4])&pfu[im][k2][0]);

#pragma unroll
    for (int dc = 0; dc < 8; ++dc) {
      const int drow = (dc * 16 + tm) * 64;       // short index of row d in V_
      const int hw = (qc & 1) * 4;                // within-chunk short offset
#pragma unroll
      for (int k2 = 0; k2 < 2; ++k2) {
        // pi: e=0..3 -> j=k2*32+qc*4+e (chunk k2*4+(qc>>1)); e=4..7 -> +16 (chunk +2)
        int sl0 = (k2 * 4 + (qc >> 1)) ^ (tm & 7);
        int sl1 = (k2 * 4 + 2 + (qc >> 1)) ^ (tm & 7);
        u64x2 c;
        c[0] = *(const u64*)&V_[drow + sl0 * 8 + hw];
        c[1] = *(const u64*)&V_[drow + sl1 * 8 + hw];
        bf16x8 vfrag = __builtin_bit_cast(bf16x8, c);
        o[0][dc] = __builtin_amdgcn_mfma_f32_16x16x32_bf16(vfrag, pf[0][k2], o[0][dc], 0, 0, 0);
        o[1][dc] = __builtin_amdgcn_mfma_f32_16x16x32_bf16(vfrag, pf[1][k2], o[1][dc], 0, 0, 0);
      }
    }
    __syncthreads();
  }

  for (int im = 0; im < 2; ++im) {
    float s = lr[im];
    s += __shfl_xor(s, 16, 64);
    s += __shfl_xor(s, 32, 64);
    float inv = 1.0f / s;
    int q = qA + im * 16;
    for (int dc = 0; dc < 8; ++dc) {
      ushort4 ov;
      ov.x = f32_to_bf16(o[im][dc][0] * inv);
      ov.y = f32_to_bf16(o[im][dc][1] * inv);
      ov.z = f32_to_bf16(o[im][dc][2] * inv);
      ov.w = f32_to_bf16(o[im][dc][3] * inv);
      *(ushort4*)&ctx[(size_t)(b * SS + q) * EE + h * DD + dc * 16 + qc * 4] = ov;
    }
  }
}

extern "C" void kernel_launch(void* const* d_in, const int* in_sizes, int n_in,
                              void* d_out, int out_size, void* d_ws, size_t ws_size,
                              hipStream_t stream) {
  const float* x  = (const float*)d_in[0];
  const float* Wq = (const float*)d_in[1];
  const float* Wk = (const float*)d_in[2];
  const float* Wv = (const float*)d_in[3];
  const float* Wo = (const float*)d_in[4];
  const float* bo = (const float*)d_in[5];
  float* out = (float*)d_out;

  const size_t XE = (size_t)BB * SS * EE;
  const size_t WE = (size_t)EE * EE;
  unsigned short* ws   = (unsigned short*)d_ws;
  unsigned short* xb   = ws;            // reused as ctx
  unsigned short* WqT  = xb + XE;       // WqT|WkT|WvT|WoT contiguous
  unsigned short* WoT  = WqT + 3 * WE;
  unsigned short* QKVb = WoT + WE;      // [B*S][3E] (V third unused now)
  unsigned short* Vt   = QKVb + 3 * XE;
  unsigned short* ctx  = xb;

  k_cast_bf16<<<XE / 1024, 256, 0, stream>>>(x, xb);
  k_transpose_w4<<<dim3(EE / 32, EE / 32, 4), 256, 0, stream>>>(Wq, Wk, Wv, Wo, WqT);

  dim3 gqkv(SE / 128, (BB * SS) / 128);  // (48, 32)
  k_gemm_bt<0><<<gqkv, 256, 0, stream>>>(xb, WqT, QKVb, nullptr, Vt, EE, SE);

  k_attn<<<dim3(BB * HH, SS / 128), 256, 0, stream>>>(QKVb, Vt, ctx);

  dim3 gg(EE / 128, (BB * SS) / 128);  // (16, 32)
  k_gemm_bt<1><<<gg, 256, 0, stream>>>(ctx, WoT, out, bo, nullptr, EE, EE);
}